// Round 1
// 1072.923 us; speedup vs baseline: 1.0725x; 1.0725x over previous
//
#include <hip/hip_runtime.h>
#include <math.h>

#define DG 256
#define DL 10
#define TN 32     // nodes per tile in k_fused
#define NBLK 512  // persistent blocks (2 per CU, LDS-limited)

__device__ __forceinline__ float leaky(float x) { return x > 0.f ? x : 0.01f * x; }
__device__ __forceinline__ float sigmoidf(float x) { return 1.f / (1.f + expf(-x)); }

// glog[b][0..9] = relu(gf[b]) . W_l1[j, 0:256] + b_l1[j]  (graph half of logit MLP).
// Rows padded to 12 floats so k_fused can read them as 3x float4.
// Also zeroes pooled[b][*] and denom[b] for this launch (replaces a memset).
__global__ void k_glog(const float* __restrict__ gf, const float* __restrict__ W_l1,
                       const float* __restrict__ b_l1, float* __restrict__ glog,
                       float* __restrict__ pooled, float* __restrict__ denom) {
  int b = blockIdx.x;
  int l = threadIdx.x;  // 64 lanes
  float4 g4 = *(const float4*)(gf + (size_t)b * DG + 4 * l);
  g4.x = fmaxf(g4.x, 0.f); g4.y = fmaxf(g4.y, 0.f);
  g4.z = fmaxf(g4.z, 0.f); g4.w = fmaxf(g4.w, 0.f);
  float p[DL];
#pragma unroll
  for (int j = 0; j < DL; ++j) {
    float4 w4 = *(const float4*)(W_l1 + (size_t)j * 512 + 4 * l);
    p[j] = g4.x * w4.x + g4.y * w4.y + g4.z * w4.z + g4.w * w4.w;
  }
#pragma unroll
  for (int m = 32; m >= 1; m >>= 1) {
#pragma unroll
    for (int j = 0; j < DL; ++j) p[j] += __shfl_xor(p[j], m);
  }
  *(float4*)(pooled + (size_t)b * 256 + 4 * l) = make_float4(0.f, 0.f, 0.f, 0.f);
  if (l == 0) {
#pragma unroll
    for (int j = 0; j < DL; ++j) glog[b * 12 + j] = p[j] + b_l1[j];
    glog[b * 12 + 10] = 0.f;
    glog[b * 12 + 11] = 0.f;
    denom[b] = 0.f;
  }
}

// Three weight transposes fused into one launch (was 3 dispatches).
// out[c*R + r] = in[r*C + c], C = 256 for all three.
__global__ void k_transpose3(const float* __restrict__ A, const float* __restrict__ Bm,
                             const float* __restrict__ C, float* __restrict__ AT,
                             float* __restrict__ BT, float* __restrict__ CT) {
  int idx = blockIdx.x * blockDim.x + threadIdx.x;  // grid sized exactly 458752
  if (idx < 65536) {                 // W_msg: 256x256
    int r = idx >> 8, c = idx & 255;
    AT[c * 256 + r] = A[idx];
  } else if (idx < 262144) {         // W_ih: 768x256
    int i = idx - 65536;
    int r = i >> 8, c = i & 255;
    BT[c * 768 + r] = Bm[i];
  } else {                           // W_hh: 768x256
    int i = idx - 262144;
    int r = i >> 8, c = i & 255;
    CT[c * 768 + r] = C[i];
  }
}

// Fused single-pass pooling: per 32-node tile, stage rows in LDS (XOR-swizzled),
// compute per-node logits with a dim-split layout (no cross-lane shuffles),
// ex = exp(lg) (UNNORMALIZED: |lg| <~ 1.5 since all weights are *0.05 scale, so no
// max-subtraction needed; identical math to the reference softmax), then
// accumulate sum(ex * x) per dim-thread with flush-on-segment-change atomics.
// k_gru divides by denom. Nodes are segment-sorted, so runs are contiguous.
//
// LDS x-tile swizzle: dim-quad (d>>2) of row r lives at f4-slot (d>>2)^(r&7).
//  - stage writes: one full 1KB row per wave-instr -> bank-even (8cy floor)
//  - phase B reads (lane=node, quad varies): 8 banks x 8 lanes x 4 words -> even
//  - phase D reads (lane=dim, row uniform): bijective over 64 words -> 2-way, free
__global__ __launch_bounds__(256) void k_fused(
    const float* __restrict__ nf, const int* __restrict__ seg,
    const float* __restrict__ W_l1, const float* __restrict__ glog,
    const float* __restrict__ W_l2, const float* __restrict__ b_l2_p,
    float* __restrict__ pooled, float* __restrict__ denom, int N) {
  __shared__ __align__(16) float xs[TN * 256];   // 32 KB swizzled node tile
  __shared__ __align__(16) float pq[TN * 84];    // 10.5 KB logit partials [n][8j+q]
  __shared__ __align__(16) float wl[DL * 256];   // 10 KB W_l1 node half
  __shared__ float sex[TN];
  __shared__ int gsg[TN];

  const int t = threadIdx.x;
  // int64 vs int32 segment_ids: N-1 is odd, so for int64 layout word N-1 is a
  // HIGH word (== 0); for int32 it's the last segment id (nonzero w.p. ~1).
  const int sstride = (seg[N - 1] == 0) ? 2 : 1;

  // one-time: stage W_l1[:, 256:512] into LDS
  for (int i = t; i < DL * 64; i += 256) {
    int j = i >> 6, c4 = i & 63;
    *(float4*)(wl + j * 256 + 4 * c4) =
        *(const float4*)(W_l1 + (size_t)j * 512 + 256 + 4 * c4);
  }
  float wl2[DL];
#pragma unroll
  for (int j = 0; j < DL; ++j) wl2[j] = W_l2[j];
  const float bl2 = b_l2_p[0];

  const int ntiles = (N + TN - 1) / TN;
  const int n = t & 31;   // phase-B node
  const int q = t >> 5;   // phase-B 32-dim quarter (0..7)
  const int sw = n & 7;

  float4 R[8];  // register-prefetched tile (T14 async-stage split)
  int tile = blockIdx.x;
  {
    const int n0 = tile * TN;
#pragma unroll
    for (int i = 0; i < 8; ++i) {
      int f4i = i * 256 + t;
      int row = f4i >> 6, col = f4i & 63;
      int gr = min(n0 + row, N - 1);
      R[i] = *(const float4*)(nf + ((size_t)gr << 8) + 4 * (col ^ (row & 7)));
    }
  }

  for (; tile < ntiles; tile += NBLK) {
    const int n0 = tile * TN;
    __syncthreads();  // prev phase D done reading xs
    // stage: regs -> LDS (full-row b128 writes, bank-even)
#pragma unroll
    for (int i = 0; i < 8; ++i) {
      int f4i = i * 256 + t;
      int row = f4i >> 6, col = f4i & 63;
      *(float4*)(xs + (row << 8) + 4 * col) = R[i];
    }
    if (t < TN) {
      int gr = min(n0 + t, N - 1);
      gsg[t] = seg[(size_t)gr * sstride];
    }
    __syncthreads();

    // prefetch next tile: loads stay in flight across phases B-D (~1200cy)
    {
      int tn2 = tile + NBLK;
      if (tn2 < ntiles) {
        const int m0 = tn2 * TN;
#pragma unroll
        for (int i = 0; i < 8; ++i) {
          int f4i = i * 256 + t;
          int row = f4i >> 6, col = f4i & 63;
          int gr = min(m0 + row, N - 1);
          R[i] = *(const float4*)(nf + ((size_t)gr << 8) + 4 * (col ^ (row & 7)));
        }
      }
    }

    // ---- phase B: logit partials, thread = (node n, 32-dim quarter q) ----
    float p[DL];
#pragma unroll
    for (int j = 0; j < DL; ++j) p[j] = 0.f;
#pragma unroll
    for (int i = 0; i < 8; ++i) {
      const float4 x4 = *(const float4*)(xs + (n << 8) + 4 * (((q << 3) + i) ^ sw));
      const float* wq = wl + (q << 5) + 4 * i;
#pragma unroll
      for (int j = 0; j < DL; ++j) {
        const float4 w4 = *(const float4*)(wq + j * 256);  // uniform -> broadcast
        p[j] += x4.x * w4.x + x4.y * w4.y + x4.z * w4.z + x4.w * w4.w;
      }
    }
#pragma unroll
    for (int j = 0; j < DL; ++j) pq[n * 84 + 8 * j + q] = p[j];
    __syncthreads();

    // ---- phase C: combine quarters, logit MLP tail, ex = exp(lg) ----
    if (t < TN) {
      const int g = gsg[t];
      const float* gp = glog + g * 12;
      float gl[12];
      *(float4*)(gl + 0) = *(const float4*)(gp + 0);
      *(float4*)(gl + 4) = *(const float4*)(gp + 4);
      *(float4*)(gl + 8) = *(const float4*)(gp + 8);
      float acc = bl2;
#pragma unroll
      for (int j = 0; j < DL; ++j) {
        const float4 a = *(const float4*)(pq + t * 84 + 8 * j);
        const float4 b4 = *(const float4*)(pq + t * 84 + 8 * j + 4);
        float s = ((a.x + a.y) + (a.z + a.w)) + ((b4.x + b4.y) + (b4.z + b4.w)) + gl[j];
        acc += wl2[j] * leaky(s);
      }
      float lg = leaky(acc);
      sex[t] = (n0 + t < N) ? expf(lg) : 0.f;
    }
    __syncthreads();

    // ---- phase D: thread t owns dim t; flush on segment change (uniform branch) ----
    {
      float acc = 0.f, accd = 0.f;
      int cur = gsg[0];
#pragma unroll 4
      for (int nn = 0; nn < TN; ++nn) {
        int g = gsg[nn];
        if (g != cur) {
          atomicAdd(pooled + ((size_t)cur << 8) + t, acc);
          if (t == 0) atomicAdd(denom + cur, accd);
          acc = 0.f; accd = 0.f; cur = g;
        }
        float e = sex[nn];
        acc += e * xs[(nn << 8) + (t ^ ((nn & 7) << 2))];
        accd += e;
      }
      atomicAdd(pooled + ((size_t)cur << 8) + t, acc);
      if (t == 0) atomicAdd(denom + cur, accd);
    }
  }
}

// GRU + output. 8 graphs per block, 256 threads.
// thread t: dims 4*dt..4*dt+3 (dt = t&63), graphs g0+{0,1} (g0 = 2*(t>>6))
__global__ __launch_bounds__(256) void k_gru(
    const float* __restrict__ pooled, const float* __restrict__ denom,
    const float* __restrict__ gf, const float* __restrict__ WmsgT,
    const float* __restrict__ b_msg, const float* __restrict__ WihT,
    const float* __restrict__ WhhT, const float* __restrict__ b_ih,
    const float* __restrict__ b_hh, float* __restrict__ out) {
  __shared__ float pool_s[8][256];
  __shared__ float gf_s[8][256];
  __shared__ float ctx_s[8][256];

  const int t = threadIdx.x;
  const int b0 = blockIdx.x * 8;
  const int dt = t & 63;
  const int g0 = (t >> 6) * 2;

  // stage normalized pooled + graph_feats
#pragma unroll
  for (int g = 0; g < 8; ++g) {
    float dn = fmaxf(denom[b0 + g], 1e-30f);
    pool_s[g][t] = pooled[(size_t)(b0 + g) * 256 + t] / dn;
    gf_s[g][t] = gf[(size_t)(b0 + g) * 256 + t];
  }
  __syncthreads();

  // ---- context = pooled @ W_msg.T + b_msg ----
  {
    float acc[2][4] = {{0.f, 0.f, 0.f, 0.f}, {0.f, 0.f, 0.f, 0.f}};
#pragma unroll 4
    for (int k = 0; k < 256; ++k) {
      float4 w = *(const float4*)(WmsgT + (size_t)k * 256 + 4 * dt);
#pragma unroll
      for (int gi = 0; gi < 2; ++gi) {
        float pv = pool_s[g0 + gi][k];
        acc[gi][0] += pv * w.x; acc[gi][1] += pv * w.y;
        acc[gi][2] += pv * w.z; acc[gi][3] += pv * w.w;
      }
    }
    float4 bm = *(const float4*)(b_msg + 4 * dt);
#pragma unroll
    for (int gi = 0; gi < 2; ++gi) {
      ctx_s[g0 + gi][4 * dt + 0] = acc[gi][0] + bm.x;
      ctx_s[g0 + gi][4 * dt + 1] = acc[gi][1] + bm.y;
      ctx_s[g0 + gi][4 * dt + 2] = acc[gi][2] + bm.z;
      ctx_s[g0 + gi][4 * dt + 3] = acc[gi][3] + bm.w;
    }
  }
  __syncthreads();

  float r[2][4], z[2][4];

  // ---- section 0: r, section 1: z ----
#pragma unroll
  for (int s = 0; s < 2; ++s) {
    float ai[2][4] = {{0.f, 0.f, 0.f, 0.f}, {0.f, 0.f, 0.f, 0.f}};
    float ah[2][4] = {{0.f, 0.f, 0.f, 0.f}, {0.f, 0.f, 0.f, 0.f}};
#pragma unroll 4
    for (int k = 0; k < 256; ++k) {
      float4 wi = *(const float4*)(WihT + (size_t)k * 768 + s * 256 + 4 * dt);
      float4 wh = *(const float4*)(WhhT + (size_t)k * 768 + s * 256 + 4 * dt);
#pragma unroll
      for (int gi = 0; gi < 2; ++gi) {
        float c = ctx_s[g0 + gi][k];
        float h = gf_s[g0 + gi][k];
        ai[gi][0] += c * wi.x; ai[gi][1] += c * wi.y; ai[gi][2] += c * wi.z; ai[gi][3] += c * wi.w;
        ah[gi][0] += h * wh.x; ah[gi][1] += h * wh.y; ah[gi][2] += h * wh.z; ah[gi][3] += h * wh.w;
      }
    }
    float4 bi = *(const float4*)(b_ih + s * 256 + 4 * dt);
    float4 bh = *(const float4*)(b_hh + s * 256 + 4 * dt);
#pragma unroll
    for (int gi = 0; gi < 2; ++gi) {
      float v0 = sigmoidf(ai[gi][0] + bi.x + ah[gi][0] + bh.x);
      float v1 = sigmoidf(ai[gi][1] + bi.y + ah[gi][1] + bh.y);
      float v2 = sigmoidf(ai[gi][2] + bi.z + ah[gi][2] + bh.z);
      float v3 = sigmoidf(ai[gi][3] + bi.w + ah[gi][3] + bh.w);
      if (s == 0) { r[gi][0] = v0; r[gi][1] = v1; r[gi][2] = v2; r[gi][3] = v3; }
      else        { z[gi][0] = v0; z[gi][1] = v1; z[gi][2] = v2; z[gi][3] = v3; }
    }
  }

  // ---- section 2: n and output ----
  {
    float ai[2][4] = {{0.f, 0.f, 0.f, 0.f}, {0.f, 0.f, 0.f, 0.f}};
    float ah[2][4] = {{0.f, 0.f, 0.f, 0.f}, {0.f, 0.f, 0.f, 0.f}};
#pragma unroll 4
    for (int k = 0; k < 256; ++k) {
      float4 wi = *(const float4*)(WihT + (size_t)k * 768 + 512 + 4 * dt);
      float4 wh = *(const float4*)(WhhT + (size_t)k * 768 + 512 + 4 * dt);
#pragma unroll
      for (int gi = 0; gi < 2; ++gi) {
        float c = ctx_s[g0 + gi][k];
        float h = gf_s[g0 + gi][k];
        ai[gi][0] += c * wi.x; ai[gi][1] += c * wi.y; ai[gi][2] += c * wi.z; ai[gi][3] += c * wi.w;
        ah[gi][0] += h * wh.x; ah[gi][1] += h * wh.y; ah[gi][2] += h * wh.z; ah[gi][3] += h * wh.w;
      }
    }
    float4 bi = *(const float4*)(b_ih + 512 + 4 * dt);
    float4 bh = *(const float4*)(b_hh + 512 + 4 * dt);
#pragma unroll
    for (int gi = 0; gi < 2; ++gi) {
      float4 o;
      float hf0 = gf_s[g0 + gi][4 * dt + 0];
      float hf1 = gf_s[g0 + gi][4 * dt + 1];
      float hf2 = gf_s[g0 + gi][4 * dt + 2];
      float hf3 = gf_s[g0 + gi][4 * dt + 3];
      float n0 = tanhf(ai[gi][0] + bi.x + r[gi][0] * (ah[gi][0] + bh.x));
      float n1 = tanhf(ai[gi][1] + bi.y + r[gi][1] * (ah[gi][1] + bh.y));
      float n2 = tanhf(ai[gi][2] + bi.z + r[gi][2] * (ah[gi][2] + bh.z));
      float n3 = tanhf(ai[gi][3] + bi.w + r[gi][3] * (ah[gi][3] + bh.w));
      o.x = (1.f - z[gi][0]) * n0 + z[gi][0] * hf0;
      o.y = (1.f - z[gi][1]) * n1 + z[gi][1] * hf1;
      o.z = (1.f - z[gi][2]) * n2 + z[gi][2] * hf2;
      o.w = (1.f - z[gi][3]) * n3 + z[gi][3] * hf3;
      // BUGFIX R2: was (b0 + gi) — dropped g0.
      *(float4*)(out + (size_t)(b0 + g0 + gi) * 256 + 4 * dt) = o;
    }
  }
}

extern "C" void kernel_launch(void* const* d_in, const int* in_sizes, int n_in,
                              void* d_out, int out_size, void* d_ws, size_t ws_size,
                              hipStream_t stream) {
  const float* nf    = (const float*)d_in[0];
  const float* gf    = (const float*)d_in[1];
  const int*   seg   = (const int*)d_in[2];
  const float* W_msg = (const float*)d_in[3];
  const float* b_msg = (const float*)d_in[4];
  const float* W_l1  = (const float*)d_in[5];
  const float* b_l1  = (const float*)d_in[6];
  const float* W_l2  = (const float*)d_in[7];
  const float* b_l2  = (const float*)d_in[8];
  const float* W_ih  = (const float*)d_in[9];
  const float* W_hh  = (const float*)d_in[10];
  const float* b_ih  = (const float*)d_in[11];
  const float* b_hh  = (const float*)d_in[12];
  float* out = (float*)d_out;

  const int N = in_sizes[0] / 256;
  const int B = in_sizes[1] / 256;

  size_t off = 0;
  char* base = (char*)d_ws;
  auto alloc = [&](size_t bytes) -> void* {
    void* p = base + off;
    off += (bytes + 255) & ~(size_t)255;
    return p;
  };
  float* glog   = (float*)alloc((size_t)B * 12 * sizeof(float));
  float* WmsgT  = (float*)alloc((size_t)256 * 256 * sizeof(float));
  float* WihT   = (float*)alloc((size_t)768 * 256 * sizeof(float));
  float* WhhT   = (float*)alloc((size_t)768 * 256 * sizeof(float));
  float* pooled = (float*)alloc((size_t)B * 256 * sizeof(float));
  float* denom  = (float*)alloc((size_t)B * sizeof(float));

  k_glog<<<B, 64, 0, stream>>>(gf, W_l1, b_l1, glog, pooled, denom);
  k_transpose3<<<(65536 + 2 * 196608 + 255) / 256, 256, 0, stream>>>(
      W_msg, W_ih, W_hh, WmsgT, WihT, WhhT);

  const int ntiles = (N + TN - 1) / TN;
  const int nblk = ntiles < NBLK ? ntiles : NBLK;
  k_fused<<<nblk, 256, 0, stream>>>(nf, seg, W_l1, glog, W_l2, b_l2, pooled, denom, N);

  k_gru<<<B / 8, 256, 0, stream>>>(pooled, denom, gf, WmsgT, b_msg, WihT, WhhT,
                                   b_ih, b_hh, out);
}

// Round 2
// 1010.774 us; speedup vs baseline: 1.1384x; 1.0615x over previous
//
#include <hip/hip_runtime.h>
#include <math.h>
#include <stdint.h>

#define DG 256
#define DL 10
#define TN 32     // nodes per tile in k_fused
#define NBLK 768  // contiguous-range blocks (3 per CU, LDS-limited)

__device__ __forceinline__ float leaky(float x) { return x > 0.f ? x : 0.01f * x; }
__device__ __forceinline__ float sigmoidf(float x) { return 1.f / (1.f + expf(-x)); }

// async global->LDS, 16B per lane. LDS dest = wave-uniform base + lane*16.
__device__ __forceinline__ void gll16(const float* src, float* dst) {
  typedef __attribute__((address_space(1))) const unsigned int gu32;
  typedef __attribute__((address_space(3))) unsigned int lu32;
  __builtin_amdgcn_global_load_lds((gu32*)src, (lu32*)dst, 16, 0, 0);
}

// glog[b][0..9] = relu(gf[b]) . W_l1[j, 0:256] + b_l1[j]  (graph half of logit MLP).
// Rows padded to 12 floats so k_fused can read 3x float4.
// Also zeroes pooled[b][*] and denom[b].
__global__ void k_glog(const float* __restrict__ gf, const float* __restrict__ W_l1,
                       const float* __restrict__ b_l1, float* __restrict__ glog,
                       float* __restrict__ pooled, float* __restrict__ denom) {
  int b = blockIdx.x;
  int l = threadIdx.x;  // 64 lanes
  float4 g4 = *(const float4*)(gf + (size_t)b * DG + 4 * l);
  g4.x = fmaxf(g4.x, 0.f); g4.y = fmaxf(g4.y, 0.f);
  g4.z = fmaxf(g4.z, 0.f); g4.w = fmaxf(g4.w, 0.f);
  float p[DL];
#pragma unroll
  for (int j = 0; j < DL; ++j) {
    float4 w4 = *(const float4*)(W_l1 + (size_t)j * 512 + 4 * l);
    p[j] = g4.x * w4.x + g4.y * w4.y + g4.z * w4.z + g4.w * w4.w;
  }
#pragma unroll
  for (int m = 32; m >= 1; m >>= 1) {
#pragma unroll
    for (int j = 0; j < DL; ++j) p[j] += __shfl_xor(p[j], m);
  }
  *(float4*)(pooled + (size_t)b * 256 + 4 * l) = make_float4(0.f, 0.f, 0.f, 0.f);
  if (l == 0) {
#pragma unroll
    for (int j = 0; j < DL; ++j) glog[b * 12 + j] = p[j] + b_l1[j];
    glog[b * 12 + 10] = 0.f;
    glog[b * 12 + 11] = 0.f;
    denom[b] = 0.f;
  }
}

// Three weight transposes fused into one launch. out[c*R + r] = in[r*C + c], C=256.
__global__ void k_transpose3(const float* __restrict__ A, const float* __restrict__ Bm,
                             const float* __restrict__ C, float* __restrict__ AT,
                             float* __restrict__ BT, float* __restrict__ CT) {
  int idx = blockIdx.x * blockDim.x + threadIdx.x;  // grid exactly 458752
  if (idx < 65536) {                 // W_msg: 256x256
    int r = idx >> 8, c = idx & 255;
    AT[c * 256 + r] = A[idx];
  } else if (idx < 262144) {         // W_ih: 768x256
    int i = idx - 65536;
    int r = i >> 8, c = i & 255;
    BT[c * 768 + r] = Bm[i];
  } else {                           // W_hh: 768x256
    int i = idx - 262144;
    int r = i >> 8, c = i & 255;
    CT[c * 768 + r] = C[i];
  }
}

// Fused single-pass pooling.
//  - Block owns a CONTIGUOUS tile range (R2: was strided -> cross-XCD atomic storm).
//  - Stage: global_load_lds 16B, swizzle applied to the GLOBAL source address
//    (slot l of row r holds logical f4 (l ^ (r&7))); single-buffered, syncthreads
//    drains vmcnt; 3 blocks/CU overlap load latency.
//  - Phase B: thread (n = t&31, q = t>>5) computes logit partials; W_l1 read from
//    GLOBAL (L1-resident 10KB) -> zero LDS traffic for weights (R2: was 320
//    LDS broadcast reads/tile = LDS-issue bound).
//  - Phase C: wave 0 combines partials, ex = exp(lg) (unnormalized; |lg|<~1.5),
//    ballot of run starts -> smask.
//  - Phase D: lane = (dim-f4 dq, node-subgroup ns); per-run lockstep accumulate;
//    carry (cur seg, acc4) in registers ACROSS tiles; flush = shfl-combine over
//    ns + atomicAdd once per (segment x dim) (~1.2M atomics total, was ~5M).
__global__ __launch_bounds__(256) void k_fused(
    const float* __restrict__ nf, const int* __restrict__ seg,
    const float* __restrict__ W_l1, const float* __restrict__ glog,
    const float* __restrict__ W_l2, const float* __restrict__ b_l2_p,
    float* __restrict__ pooled, float* __restrict__ denom, int N) {
  __shared__ __align__(16) float xs[TN * 256];  // 32 KB swizzled node tile
  __shared__ __align__(16) float pq[TN * 84];   // 10.5 KB logit partials, 16B-mult stride
  __shared__ float sex[TN];
  __shared__ int gsg[TN];
  __shared__ unsigned smask;

  const int t = threadIdx.x;
  const int l = t & 63;
  const int w = t >> 6;
  // int64 vs int32 segment_ids: N-1 odd -> word N-1 is int64 HIGH word (==0).
  const int sstride = (seg[N - 1] == 0) ? 2 : 1;

  const int ntiles = (N + TN - 1) / TN;
  const int q0 = ntiles / NBLK, r0 = ntiles % NBLK;
  const int bid = blockIdx.x;
  const int tile_lo = bid * q0 + (bid < r0 ? bid : r0);
  const int tile_hi = tile_lo + q0 + (bid < r0 ? 1 : 0);

  // phase-B ids
  const int nB = t & 31, qB = t >> 5;
  const int swB = nB & 7;
  // phase-D ids
  const int dq = (w << 4) + (l & 15);  // f4 index 0..63 (dims 4dq..4dq+3)
  const int ns = l >> 4;               // node subgroup: nodes 8ns..8ns+7
  const bool dlane = (w == 0) && ((l & 15) == 0);  // counts denom, one lane per ns

  float wl2[DL];
#pragma unroll
  for (int j = 0; j < DL; ++j) wl2[j] = W_l2[j];
  const float bl2 = b_l2_p[0];

  // carried segment accumulator
  float ax = 0.f, ay = 0.f, az = 0.f, aw = 0.f, ad = 0.f;
  int cur = -1;

  for (int tile = tile_lo; tile < tile_hi; ++tile) {
    const int n0 = tile * TN;
    __syncthreads();  // prev phase D done reading xs/sex/gsg

    // ---- stage: wave w stages rows 8w..8w+7 via global_load_lds ----
#pragma unroll
    for (int rr = 0; rr < 8; ++rr) {
      const int r = (w << 3) + rr;
      int gr = n0 + r; if (gr > N - 1) gr = N - 1;
      const float* src = nf + ((size_t)gr << 8) + 4 * (l ^ (r & 7));
      gll16(src, xs + (r << 8));
    }
    if (t < TN) {
      int gr = n0 + t; if (gr > N - 1) gr = N - 1;
      gsg[t] = seg[(size_t)gr * sstride];
    }
    __syncthreads();  // drains vmcnt(0)+lgkmcnt(0): xs, gsg ready

    // ---- phase B: logit partials; weights from global (L1 hits) ----
    {
      float p[DL];
#pragma unroll
      for (int j = 0; j < DL; ++j) p[j] = 0.f;
      const float* wbase = W_l1 + 256 + (qB << 5);
#pragma unroll 2
      for (int i = 0; i < 8; ++i) {
        const float4 x4 =
            *(const float4*)(xs + (nB << 8) + 4 * (((qB << 3) + i) ^ swB));
#pragma unroll
        for (int j = 0; j < DL; ++j) {
          const float4 w4 = *(const float4*)(wbase + (size_t)j * 512 + 4 * i);
          p[j] += x4.x * w4.x + x4.y * w4.y + x4.z * w4.z + x4.w * w4.w;
        }
      }
#pragma unroll
      for (int j = 0; j < DL; ++j) pq[nB * 84 + 8 * j + qB] = p[j];
    }
    __syncthreads();

    // ---- phase C (wave 0): combine, MLP tail, ex = exp(lg), run mask ----
    if (t < 64) {
      bool strt = false;
      if (t < TN) {
        const int g = gsg[t];
        const float* gp = glog + g * 12;
        float gl[12];
        *(float4*)(gl + 0) = *(const float4*)(gp + 0);
        *(float4*)(gl + 4) = *(const float4*)(gp + 4);
        *(float4*)(gl + 8) = *(const float4*)(gp + 8);
        float acc = bl2;
#pragma unroll
        for (int j = 0; j < DL; ++j) {
          const float4 a = *(const float4*)(pq + t * 84 + 8 * j);
          const float4 b4 = *(const float4*)(pq + t * 84 + 8 * j + 4);
          float s = ((a.x + a.y) + (a.z + a.w)) + ((b4.x + b4.y) + (b4.z + b4.w)) + gl[j];
          acc += wl2[j] * leaky(s);
        }
        float lg = leaky(acc);
        sex[t] = (n0 + t < N) ? expf(lg) : 0.f;
        strt = (t == 0) || (gsg[t] != gsg[t - 1]);
      }
      unsigned long long bm = __ballot(strt);
      if (t == 0) smask = (unsigned)bm;
    }
    __syncthreads();

    // ---- phase D: run-based accumulate with cross-tile register carry ----
    {
      const unsigned m = smask;
      int a = 0;
      while (a < TN) {
        const int g = gsg[a];  // uniform broadcast
        const unsigned rest = (a < 31) ? (m >> (a + 1)) : 0u;
        const int b = rest ? (a + __ffs(rest)) : TN;
        if (g != cur) {
          // flush carried segment (uniform branch)
          if (cur >= 0) {
            float vx = ax, vy = ay, vz = az, vw = aw, vd = ad;
            vx += __shfl_xor(vx, 16); vy += __shfl_xor(vy, 16);
            vz += __shfl_xor(vz, 16); vw += __shfl_xor(vw, 16);
            vd += __shfl_xor(vd, 16);
            vx += __shfl_xor(vx, 32); vy += __shfl_xor(vy, 32);
            vz += __shfl_xor(vz, 32); vw += __shfl_xor(vw, 32);
            vd += __shfl_xor(vd, 32);
            if ((l & 48) == 0) {  // ns == 0 lanes: 16 per wave, 64 dims/wave
              float* p = pooled + ((size_t)cur << 8) + 4 * dq;
              atomicAdd(p + 0, vx); atomicAdd(p + 1, vy);
              atomicAdd(p + 2, vz); atomicAdd(p + 3, vw);
            }
            if (t == 0) atomicAdd(denom + cur, vd);
          }
          ax = ay = az = aw = ad = 0.f;
          cur = g;
        }
#pragma unroll
        for (int k = 0; k < 8; ++k) {
          const int node = (ns << 3) + k;
          const bool act = (node >= a) && (node < b);
          float e = sex[node];
          e = act ? e : 0.f;
          const float4 x4 =
              *(const float4*)(xs + (node << 8) + 4 * (dq ^ (node & 7)));
          ax += e * x4.x; ay += e * x4.y; az += e * x4.z; aw += e * x4.w;
          ad += dlane ? e : 0.f;
        }
        a = b;
      }
    }
  }

  // final flush of carried segment
  if (cur >= 0) {
    float vx = ax, vy = ay, vz = az, vw = aw, vd = ad;
    vx += __shfl_xor(vx, 16); vy += __shfl_xor(vy, 16);
    vz += __shfl_xor(vz, 16); vw += __shfl_xor(vw, 16);
    vd += __shfl_xor(vd, 16);
    vx += __shfl_xor(vx, 32); vy += __shfl_xor(vy, 32);
    vz += __shfl_xor(vz, 32); vw += __shfl_xor(vw, 32);
    vd += __shfl_xor(vd, 32);
    if ((l & 48) == 0) {
      float* p = pooled + ((size_t)cur << 8) + 4 * dq;
      atomicAdd(p + 0, vx); atomicAdd(p + 1, vy);
      atomicAdd(p + 2, vz); atomicAdd(p + 3, vw);
    }
    if (t == 0) atomicAdd(denom + cur, vd);
  }
}

// GRU + output. 8 graphs per block, 256 threads.
// thread t: dims 4*dt..4*dt+3 (dt = t&63), graphs g0+{0,1} (g0 = 2*(t>>6))
__global__ __launch_bounds__(256) void k_gru(
    const float* __restrict__ pooled, const float* __restrict__ denom,
    const float* __restrict__ gf, const float* __restrict__ WmsgT,
    const float* __restrict__ b_msg, const float* __restrict__ WihT,
    const float* __restrict__ WhhT, const float* __restrict__ b_ih,
    const float* __restrict__ b_hh, float* __restrict__ out) {
  __shared__ float pool_s[8][256];
  __shared__ float gf_s[8][256];
  __shared__ float ctx_s[8][256];

  const int t = threadIdx.x;
  const int b0 = blockIdx.x * 8;
  const int dt = t & 63;
  const int g0 = (t >> 6) * 2;

#pragma unroll
  for (int g = 0; g < 8; ++g) {
    float dn = fmaxf(denom[b0 + g], 1e-30f);
    pool_s[g][t] = pooled[(size_t)(b0 + g) * 256 + t] / dn;
    gf_s[g][t] = gf[(size_t)(b0 + g) * 256 + t];
  }
  __syncthreads();

  // ---- context = pooled @ W_msg.T + b_msg ----
  {
    float acc[2][4] = {{0.f, 0.f, 0.f, 0.f}, {0.f, 0.f, 0.f, 0.f}};
#pragma unroll 4
    for (int k = 0; k < 256; ++k) {
      float4 wv = *(const float4*)(WmsgT + (size_t)k * 256 + 4 * dt);
#pragma unroll
      for (int gi = 0; gi < 2; ++gi) {
        float pv = pool_s[g0 + gi][k];
        acc[gi][0] += pv * wv.x; acc[gi][1] += pv * wv.y;
        acc[gi][2] += pv * wv.z; acc[gi][3] += pv * wv.w;
      }
    }
    float4 bm = *(const float4*)(b_msg + 4 * dt);
#pragma unroll
    for (int gi = 0; gi < 2; ++gi) {
      ctx_s[g0 + gi][4 * dt + 0] = acc[gi][0] + bm.x;
      ctx_s[g0 + gi][4 * dt + 1] = acc[gi][1] + bm.y;
      ctx_s[g0 + gi][4 * dt + 2] = acc[gi][2] + bm.z;
      ctx_s[g0 + gi][4 * dt + 3] = acc[gi][3] + bm.w;
    }
  }
  __syncthreads();

  float r[2][4], z[2][4];

#pragma unroll
  for (int s = 0; s < 2; ++s) {
    float ai[2][4] = {{0.f, 0.f, 0.f, 0.f}, {0.f, 0.f, 0.f, 0.f}};
    float ah[2][4] = {{0.f, 0.f, 0.f, 0.f}, {0.f, 0.f, 0.f, 0.f}};
#pragma unroll 4
    for (int k = 0; k < 256; ++k) {
      float4 wi = *(const float4*)(WihT + (size_t)k * 768 + s * 256 + 4 * dt);
      float4 wh = *(const float4*)(WhhT + (size_t)k * 768 + s * 256 + 4 * dt);
#pragma unroll
      for (int gi = 0; gi < 2; ++gi) {
        float c = ctx_s[g0 + gi][k];
        float h = gf_s[g0 + gi][k];
        ai[gi][0] += c * wi.x; ai[gi][1] += c * wi.y; ai[gi][2] += c * wi.z; ai[gi][3] += c * wi.w;
        ah[gi][0] += h * wh.x; ah[gi][1] += h * wh.y; ah[gi][2] += h * wh.z; ah[gi][3] += h * wh.w;
      }
    }
    float4 bi = *(const float4*)(b_ih + s * 256 + 4 * dt);
    float4 bh = *(const float4*)(b_hh + s * 256 + 4 * dt);
#pragma unroll
    for (int gi = 0; gi < 2; ++gi) {
      float v0 = sigmoidf(ai[gi][0] + bi.x + ah[gi][0] + bh.x);
      float v1 = sigmoidf(ai[gi][1] + bi.y + ah[gi][1] + bh.y);
      float v2 = sigmoidf(ai[gi][2] + bi.z + ah[gi][2] + bh.z);
      float v3 = sigmoidf(ai[gi][3] + bi.w + ah[gi][3] + bh.w);
      if (s == 0) { r[gi][0] = v0; r[gi][1] = v1; r[gi][2] = v2; r[gi][3] = v3; }
      else        { z[gi][0] = v0; z[gi][1] = v1; z[gi][2] = v2; z[gi][3] = v3; }
    }
  }

  {
    float ai[2][4] = {{0.f, 0.f, 0.f, 0.f}, {0.f, 0.f, 0.f, 0.f}};
    float ah[2][4] = {{0.f, 0.f, 0.f, 0.f}, {0.f, 0.f, 0.f, 0.f}};
#pragma unroll 4
    for (int k = 0; k < 256; ++k) {
      float4 wi = *(const float4*)(WihT + (size_t)k * 768 + 512 + 4 * dt);
      float4 wh = *(const float4*)(WhhT + (size_t)k * 768 + 512 + 4 * dt);
#pragma unroll
      for (int gi = 0; gi < 2; ++gi) {
        float c = ctx_s[g0 + gi][k];
        float h = gf_s[g0 + gi][k];
        ai[gi][0] += c * wi.x; ai[gi][1] += c * wi.y; ai[gi][2] += c * wi.z; ai[gi][3] += c * wi.w;
        ah[gi][0] += h * wh.x; ah[gi][1] += h * wh.y; ah[gi][2] += h * wh.z; ah[gi][3] += h * wh.w;
      }
    }
    float4 bi = *(const float4*)(b_ih + 512 + 4 * dt);
    float4 bh = *(const float4*)(b_hh + 512 + 4 * dt);
#pragma unroll
    for (int gi = 0; gi < 2; ++gi) {
      float4 o;
      float hf0 = gf_s[g0 + gi][4 * dt + 0];
      float hf1 = gf_s[g0 + gi][4 * dt + 1];
      float hf2 = gf_s[g0 + gi][4 * dt + 2];
      float hf3 = gf_s[g0 + gi][4 * dt + 3];
      float n0 = tanhf(ai[gi][0] + bi.x + r[gi][0] * (ah[gi][0] + bh.x));
      float n1 = tanhf(ai[gi][1] + bi.y + r[gi][1] * (ah[gi][1] + bh.y));
      float n2 = tanhf(ai[gi][2] + bi.z + r[gi][2] * (ah[gi][2] + bh.z));
      float n3 = tanhf(ai[gi][3] + bi.w + r[gi][3] * (ah[gi][3] + bh.w));
      o.x = (1.f - z[gi][0]) * n0 + z[gi][0] * hf0;
      o.y = (1.f - z[gi][1]) * n1 + z[gi][1] * hf1;
      o.z = (1.f - z[gi][2]) * n2 + z[gi][2] * hf2;
      o.w = (1.f - z[gi][3]) * n3 + z[gi][3] * hf3;
      *(float4*)(out + (size_t)(b0 + g0 + gi) * 256 + 4 * dt) = o;
    }
  }
}

extern "C" void kernel_launch(void* const* d_in, const int* in_sizes, int n_in,
                              void* d_out, int out_size, void* d_ws, size_t ws_size,
                              hipStream_t stream) {
  const float* nf    = (const float*)d_in[0];
  const float* gf    = (const float*)d_in[1];
  const int*   seg   = (const int*)d_in[2];
  const float* W_msg = (const float*)d_in[3];
  const float* b_msg = (const float*)d_in[4];
  const float* W_l1  = (const float*)d_in[5];
  const float* b_l1  = (const float*)d_in[6];
  const float* W_l2  = (const float*)d_in[7];
  const float* b_l2  = (const float*)d_in[8];
  const float* W_ih  = (const float*)d_in[9];
  const float* W_hh  = (const float*)d_in[10];
  const float* b_ih  = (const float*)d_in[11];
  const float* b_hh  = (const float*)d_in[12];
  float* out = (float*)d_out;

  const int N = in_sizes[0] / 256;
  const int B = in_sizes[1] / 256;

  size_t off = 0;
  char* base = (char*)d_ws;
  auto alloc = [&](size_t bytes) -> void* {
    void* p = base + off;
    off += (bytes + 255) & ~(size_t)255;
    return p;
  };
  float* glog   = (float*)alloc((size_t)B * 12 * sizeof(float));
  float* WmsgT  = (float*)alloc((size_t)256 * 256 * sizeof(float));
  float* WihT   = (float*)alloc((size_t)768 * 256 * sizeof(float));
  float* WhhT   = (float*)alloc((size_t)768 * 256 * sizeof(float));
  float* pooled = (float*)alloc((size_t)B * 256 * sizeof(float));
  float* denom  = (float*)alloc((size_t)B * sizeof(float));

  k_glog<<<B, 64, 0, stream>>>(gf, W_l1, b_l1, glog, pooled, denom);
  k_transpose3<<<(65536 + 2 * 196608 + 255) / 256, 256, 0, stream>>>(
      W_msg, W_ih, W_hh, WmsgT, WihT, WhhT);

  k_fused<<<NBLK, 256, 0, stream>>>(nf, seg, W_l1, glog, W_l2, b_l2, pooled,
                                    denom, N);

  k_gru<<<B / 8, 256, 0, stream>>>(pooled, denom, gf, WmsgT, b_msg, WihT, WhhT,
                                   b_ih, b_hh, out);
}